// Round 16
// baseline (253.271 us; speedup 1.0000x reference)
//
#include <hip/hip_runtime.h>
#include <math.h>

#define N_HEADC  16
#define D_MODELC 1024
#define ATTN_N_C    3145728
#define ATTN_PAD_C  4194304
#define ATTN_NC     2097152   // half-size complex FFT length (2^21 = 8^7)
#define ATTN_KEEP_C 524288
#define PROJ_N_C    1048576
#define PROJ_PAD_C  1048576
#define PROJ_NC     524288    // 2^19 = 2 * 8^6
#define PROJ_KEEP_C 131072
#define BATCH_C 2
#define SEQ_C   2048

// 0.125 * log2(e): folded into Wa's Q-columns + Q-bias so attn does exp2(s)
#define CEXP_C 0.18033688011112042f

typedef __attribute__((ext_vector_type(8))) short s16x8;
typedef __attribute__((ext_vector_type(4))) float f32x4;

#define AS1U(p) ((const __attribute__((address_space(1))) uint*)(p))
#define AS3U(p) ((__attribute__((address_space(3))) uint*)(p))

static __device__ __forceinline__ ushort f2bf(float f) {
    __bf16 b = (__bf16)f;
    return __builtin_bit_cast(ushort, b);
}
static __device__ __forceinline__ float bf2f(ushort u) {
    return __builtin_bit_cast(float, ((uint)u) << 16);
}
static __device__ __forceinline__ float2 cmul(float2 a, float2 b) {
    return make_float2(a.x * b.x - a.y * b.y, a.x * b.y + a.y * b.x);
}
static __device__ __forceinline__ float2 cadd(float2 a, float2 b) {
    return make_float2(a.x + b.x, a.y + b.y);
}
static __device__ __forceinline__ float2 csub(float2 a, float2 b) {
    return make_float2(a.x - b.x, a.y - b.y);
}
static __device__ __forceinline__ float2 crot(float2 z) {   // i*z
    return make_float2(-z.y, z.x);
}

// ---------------------------------------------------------------------------
// R31: sincos in REVOLUTIONS via raw v_sin/v_cos. Every FFT angle here is
// (exact binary fraction) of a revolution (power-of-2 denominators, args
// < 1) -> no range reduction needed; OCML __sincosf's ~10-op reduction
// path replaced by mul + v_sin + v_cos. Revolution args are EXACTLY
// representable (radians path rounds th0). rcp of pow2 M is exact.
// ---------------------------------------------------------------------------
static __device__ __forceinline__ void sincos_rev(float rev, float* si, float* co) {
    *si = __builtin_amdgcn_sinf(rev);   // sin(2*pi*rev)
    *co = __builtin_amdgcn_cosf(rev);   // cos(2*pi*rev)
}

// 8-point inverse DFT core (verified R9). a[0..7] -> B[0..7] (pre-twiddle).
static __device__ __forceinline__ void r8core(const float2* a, float2* B) {
    const float2 t0 = cadd(a[0], a[4]), t1 = csub(a[0], a[4]);
    const float2 t2 = cadd(a[2], a[6]), t3 = csub(a[2], a[6]);
    const float2 t4 = cadd(a[1], a[5]), t5 = csub(a[1], a[5]);
    const float2 t6 = cadd(a[3], a[7]), t7 = csub(a[3], a[7]);
    const float2 E0 = cadd(t0, t2), E2 = csub(t0, t2);
    const float2 E1 = cadd(t1, crot(t3)), E3 = csub(t1, crot(t3));
    const float2 F0 = cadd(t4, t6), F2 = csub(t4, t6);
    const float2 F1 = cadd(t5, crot(t7)), F3 = csub(t5, crot(t7));
    const float c = 0.70710678118654752f;
    const float2 G1 = make_float2(c * (F1.x - F1.y), c * (F1.x + F1.y));   // c(1+i)F1
    const float2 G2 = crot(F2);                                            // iF2
    const float2 G3 = make_float2(c * (-F3.x - F3.y), c * (F3.x - F3.y));  // c(-1+i)F3
    B[0] = cadd(E0, F0); B[4] = csub(E0, F0);
    B[1] = cadd(E1, G1); B[5] = csub(E1, G1);
    B[2] = cadd(E2, G2); B[6] = csub(E2, G2);
    B[3] = cadd(E3, G3); B[7] = csub(E3, G3);
}

// pack: threv = 1/PAD (exact pow2 fraction); rev = k*threv < 0.5
static __device__ __forceinline__ float2 pack_eval(
    const float2* __restrict__ H, int Nc, float threv, int k) {
    float2 g = H[k];
    float2 hm = H[Nc - k];
    if (k == 0) { g.y = 0.f; hm.y = 0.f; }
    float2 gh = make_float2(hm.x, -hm.y);
    float2 sum = make_float2(g.x + gh.x, g.y + gh.y);
    float2 dif = make_float2(g.x - gh.x, g.y - gh.y);
    float si, co;
    sincos_rev(threv * (float)k, &si, &co);
    float2 t = make_float2(dif.x * co - dif.y * si, dif.x * si + dif.y * co);
    return make_float2(sum.x - t.y, sum.y + t.x);
}

// proj stage 1: radix-2 peel with pack fused. twiddle rev = t/(2m).
static __device__ __forceinline__ void r2_pack_body(
    const float2* __restrict__ H, float2* __restrict__ out,
    int Nc, float threv, int m, int half, int t) {
    if (t >= half) return;
    float2 a = pack_eval(H, Nc, threv, t);
    float2 b = pack_eval(H, Nc, threv, t + m);
    float si, co;
    const float mrev = 0.5f * __builtin_amdgcn_rcpf((float)m);  // exact pow2
    sincos_rev((float)t * mrev, &si, &co);
    float2 su = cadd(a, b);
    float2 di = csub(a, b);
    out[2 * t]     = su;
    out[2 * t + 1] = make_float2(di.x * co - di.y * si, di.x * si + di.y * co);
}

// radix-8 final pass: ang0rev = 1/8; rev = p/8 < 1.
static __device__ __forceinline__ void r8_body(
    const float2* __restrict__ in, float2* __restrict__ out,
    int slog, int M, float ang0rev, int eighth, int t) {
    if (t >= eighth) return;
    const int s = 1 << slog;
    const int q = t & (s - 1);
    const int p = t >> slog;
    float2 a[8];
#pragma unroll
    for (int j = 0; j < 8; ++j)
        a[j] = in[q + (size_t)s * (p + j * M)];
    float2 B[8];
    r8core(a, B);
    float si, co;
    sincos_rev(ang0rev * (float)p, &si, &co);
    const float2 w = make_float2(co, si);
    const int ob = q + 8 * s * p;
    out[ob] = B[0];
    float2 wj = w;
    out[ob + s] = cmul(wj, B[1]);
#pragma unroll
    for (int j = 2; j < 8; ++j) {
        wj = cmul(wj, w);
        out[ob + j * s] = cmul(wj, B[j]);
    }
}

// radix-64: w rev = p/(8M) = p*invM/8; w2 rev = p0/M = p0*invM. invM exact.
static __device__ void r64_body(
    float2 (*Ysh)[8][9],
    const float2* __restrict__ in, float2* __restrict__ out,
    int slog, int M, int vb) {
    const int tid = threadIdx.x;
    const int g = tid & 31, u = tid >> 5;
    const int s = 1 << slog;
    const int M8 = M >> 3;
    const int G = vb * 32 + g;
    const int q = G & (s - 1);
    const int p0 = G >> slog;
    const float invM = __builtin_amdgcn_rcpf((float)M);   // exact pow2

    const int p = p0 + u * M8;
    float2 a[8];
#pragma unroll
    for (int j = 0; j < 8; ++j)
        a[j] = in[q + (size_t)s * (p + j * M)];
    float2 B[8];
    r8core(a, B);
    float si, co;
    sincos_rev(0.125f * invM * (float)p, &si, &co);       // p/(8M)
    const float2 w = make_float2(co, si);
    Ysh[g][u][0] = B[0];
    float2 wj = w;
    Ysh[g][u][1] = cmul(wj, B[1]);
#pragma unroll
    for (int j = 2; j < 8; ++j) {
        wj = cmul(wj, w);
        Ysh[g][u][j] = cmul(wj, B[j]);
    }
    __syncthreads();

    float2 z[8];
#pragma unroll
    for (int jp = 0; jp < 8; ++jp)
        z[jp] = Ysh[g][jp][u];
    float2 B2[8];
    r8core(z, B2);
    sincos_rev(invM * (float)p0, &si, &co);               // p0/(8*M8) = p0/M
    const float2 w2 = make_float2(co, si);
    const size_t ob = (size_t)q + (size_t)u * s + (size_t)64 * s * p0;
    out[ob] = B2[0];
    float2 wj2 = w2;
    out[ob + (size_t)8 * s] = cmul(wj2, B2[1]);
#pragma unroll
    for (int j2 = 2; j2 < 8; ++j2) {
        wj2 = cmul(wj2, w2);
        out[ob + (size_t)j2 * 8 * s] = cmul(wj2, B2[j2]);
    }
}

// attn stage 1: radix-64 with pack fused (slog=0: s=1, q=0, element p+jM)
static __device__ void r64_pack_body(
    float2 (*Ysh)[8][9],
    const float2* __restrict__ H, float2* __restrict__ out,
    int Nc, float threv, int M, int vb) {
    const int tid = threadIdx.x;
    const int g = tid & 31, u = tid >> 5;
    const int M8 = M >> 3;
    const int p0 = vb * 32 + g;
    const int p = p0 + u * M8;
    const float invM = __builtin_amdgcn_rcpf((float)M);   // exact pow2
    float2 a[8];
#pragma unroll
    for (int j = 0; j < 8; ++j)
        a[j] = pack_eval(H, Nc, threv, p + j * M);
    float2 B[8];
    r8core(a, B);
    float si, co;
    sincos_rev(0.125f * invM * (float)p, &si, &co);       // p/(8M)
    const float2 w = make_float2(co, si);
    Ysh[g][u][0] = B[0];
    float2 wj = w;
    Ysh[g][u][1] = cmul(wj, B[1]);
#pragma unroll
    for (int j = 2; j < 8; ++j) {
        wj = cmul(wj, w);
        Ysh[g][u][j] = cmul(wj, B[j]);
    }
    __syncthreads();

    float2 z[8];
#pragma unroll
    for (int jp = 0; jp < 8; ++jp)
        z[jp] = Ysh[g][jp][u];
    float2 B2[8];
    r8core(z, B2);
    sincos_rev(invM * (float)p0, &si, &co);               // p0/M
    const float2 w2 = make_float2(co, si);
    const size_t ob = (size_t)u + (size_t)64 * p0;
    out[ob] = B2[0];
    float2 wj2 = w2;
    out[ob + 8] = cmul(wj2, B2[1]);
#pragma unroll
    for (int j2 = 2; j2 < 8; ++j2) {
        wj2 = cmul(wj2, w2);
        out[ob + (size_t)j2 * 8] = cmul(wj2, B2[j2]);
    }
}

static __device__ __forceinline__ void transpose_body(
    float (*T)[33], const float2* __restrict__ z, ushort* __restrict__ WT,
    int Kd, int Nd, float inv, const float* __restrict__ sc, int qcols, int vb) {
    const int nbx = Nd >> 5;
    const int n0 = (vb % nbx) * 32, k0 = (vb / nbx) * 32;
    const int tx = threadIdx.x & 31, ty = threadIdx.x >> 5;
    const float s = inv * sc[0];
    for (int r = ty; r < 32; r += 8) {
        size_t j = (size_t)(k0 + r) * Nd + n0 + tx;
        float2 zz = z[j >> 1];
        T[r][tx] = (j & 1) ? zz.y : zz.x;
    }
    __syncthreads();
    for (int r = ty; r < 32; r += 8) {
        const float fs = ((n0 + r) < qcols) ? s * CEXP_C : s;
        WT[(size_t)(n0 + r) * Kd + k0 + tx] = f2bf(T[tx][r] * fs);
    }
}

// ---- merged dispatch kernels ----

// x->bf16 (4096 blocks) ∥ spectral scatter (2560 blocks)
__global__ __launch_bounds__(256) void x_scatter(
    const float* __restrict__ x, ushort* __restrict__ xb,
    const float* __restrict__ re_a, const float* __restrict__ im_a,
    const int* __restrict__ idx_a, float2* __restrict__ Ha,
    const float* __restrict__ re_p, const float* __restrict__ im_p,
    const int* __restrict__ idx_p, float2* __restrict__ Hp) {
    const int B = blockIdx.x;
    if (B < 4096) {
        const int i = B * 256 + threadIdx.x;
        float4 v = *(const float4*)(x + (size_t)i * 4);
        ushort4 o;
        o.x = f2bf(v.x); o.y = f2bf(v.y); o.z = f2bf(v.z); o.w = f2bf(v.w);
        *(ushort4*)(xb + (size_t)i * 4) = o;
    } else {
        const int t = (B - 4096) * 256 + threadIdx.x;
        if (t < ATTN_KEEP_C) {
            Ha[idx_a[t]] = make_float2(re_a[t], im_a[t]);
        } else {
            const int u = t - ATTN_KEEP_C;
            Hp[idx_p[u]] = make_float2(re_p[u], im_p[u]);
        }
    }
}

// FUSED stage 1: attn pack+r64 (1024 blocks) ∥ proj pack+r2 (1024 blocks)
__global__ __launch_bounds__(256) void fft_pack1(
    const float2* __restrict__ Ha, float2* __restrict__ oa, float tha, int na,
    const float2* __restrict__ Hp, float2* __restrict__ op, float thp,
    int mp, int halfp) {
    __shared__ float2 Ysh[32][8][9];
    if ((int)blockIdx.x < na)
        r64_pack_body(Ysh, Ha, oa, ATTN_NC, tha, ATTN_NC >> 3, blockIdx.x);
    else
        r2_pack_body(Hp, op, PROJ_NC, thp, mp, halfp,
                     (blockIdx.x - na) * 256 + threadIdx.x);
}

// attn r64 ∥ proj r64
__global__ __launch_bounds__(256) void fft_r64_dual(
    const float2* __restrict__ ia, float2* __restrict__ oa, int sla, int Ma, int na,
    const float2* __restrict__ ip, float2* __restrict__ op, int slp, int Mp) {
    __shared__ float2 Ysh[32][8][9];
    if ((int)blockIdx.x < na)
        r64_body(Ysh, ia, oa, sla, Ma, blockIdx.x);
    else
        r64_body(Ysh, ip, op, slp, Mp, blockIdx.x - na);
}

// attn r8 final ∥ proj r64 final
__global__ __launch_bounds__(256) void fft_r8_r64(
    const float2* __restrict__ ia, float2* __restrict__ oa, int sla, float ang0rev,
    int eighth, int na,
    const float2* __restrict__ ip, float2* __restrict__ op, int slp, int Mp) {
    __shared__ float2 Ysh[32][8][9];
    if ((int)blockIdx.x < na)
        r8_body(ia, oa, sla, 1, ang0rev, eighth, (blockIdx.x) * 256 + threadIdx.x);
    else
        r64_body(Ysh, ip, op, slp, Mp, blockIdx.x - na);
}

// transpose attn (3072 tiles) ∥ transpose proj (1024 tiles)
__global__ __launch_bounds__(256) void transpose_dual(
    const float2* __restrict__ za, ushort* __restrict__ Wa, const float* __restrict__ sca,
    const float2* __restrict__ zp, ushort* __restrict__ Wp, const float* __restrict__ scp) {
    __shared__ float T[32][33];
    if (blockIdx.x < 3072)
        transpose_body(T, za, Wa, 1024, 3072, 1.f / ATTN_PAD_C, sca, 1024, blockIdx.x);
    else
        transpose_body(T, zp, Wp, 1024, 1024, 1.f / PROJ_PAD_C, scp, 0, blockIdx.x - 3072);
}

// ---------------------------------------------------------------------------
// bf16 MFMA GEMM v5 (R21): BK=64 + 2-D grid (default mapping already puts
// all 32 B-panel sharers on one XCD). OUTMODE==1: Q-bias fold.
// ---------------------------------------------------------------------------
template <int OUTMODE>
__global__ __launch_bounds__(256) void gemm_bt_mfma(
    const ushort* __restrict__ A, const ushort* __restrict__ Bt,
    const float* __restrict__ bias, void* __restrict__ Cout,
    ushort* __restrict__ Vt, int M, int N, int K) {
    __shared__ ushort As[128 * 64];
    __shared__ ushort Bs[128 * 64];
    const int tid = threadIdx.x;
    const int wid = tid >> 6, lane = tid & 63, quad = lane >> 4, l16 = lane & 15;
    const int row0 = blockIdx.y * 128, col0 = blockIdx.x * 128;
    const int mh = (wid >> 1) * 64, nh = (wid & 1) * 64;
    const int r7 = l16 & 7;

    f32x4 acc[4][4] = {};

    for (int k0 = 0; k0 < K; k0 += 64) {
        __syncthreads();
#pragma unroll
        for (int rep = 0; rep < 4; ++rep) {
            int c = tid + rep * 256;
            int r = c >> 3;
            int kc = (c & 7) ^ (r & 7);
            ushort* lbA = &As[(rep * 256 + wid * 64) * 8];
            ushort* lbB = &Bs[(rep * 256 + wid * 64) * 8];
            __builtin_amdgcn_global_load_lds(
                AS1U(A + (size_t)(row0 + r) * K + k0 + kc * 8), AS3U(lbA), 16, 0, 0);
            __builtin_amdgcn_global_load_lds(
                AS1U(Bt + (size_t)(col0 + r) * K + k0 + kc * 8), AS3U(lbB), 16, 0, 0);
        }
        __syncthreads();
#pragma unroll
        for (int kk = 0; kk < 2; ++kk) {
            const int slot = ((kk * 4 + quad) ^ r7) * 8;
            s16x8 af[4], bfr[4];
#pragma unroll
            for (int mi = 0; mi < 4; ++mi)
                af[mi] = *(const s16x8*)&As[(mh + mi * 16 + l16) * 64 + slot];
#pragma unroll
            for (int ni = 0; ni < 4; ++ni)
                bfr[ni] = *(const s16x8*)&Bs[(nh + ni * 16 + l16) * 64 + slot];
#pragma unroll
            for (int mi = 0; mi < 4; ++mi)
#pragma unroll
                for (int ni = 0; ni < 4; ++ni)
                    acc[mi][ni] = __builtin_amdgcn_mfma_f32_16x16x32_bf16(
                        af[mi], bfr[ni], acc[mi][ni], 0, 0, 0);
        }
    }

#pragma unroll
    for (int mi = 0; mi < 4; ++mi)
#pragma unroll
        for (int ni = 0; ni < 4; ++ni) {
            const int col = col0 + nh + ni * 16 + l16;
            const int rbase = row0 + mh + mi * 16 + quad * 4;
            float bv = bias[col];
            if (OUTMODE == 1 && col < 1024) bv *= CEXP_C;   // Q-bias fold
            if (OUTMODE == 0) {
                float* C = (float*)Cout;
#pragma unroll
                for (int j = 0; j < 4; ++j)
                    C[(size_t)(rbase + j) * N + col] = acc[mi][ni][j] + bv;
            } else {
                if (col < 2048) {
                    ushort* C = (ushort*)Cout;
#pragma unroll
                    for (int j = 0; j < 4; ++j)
                        C[(size_t)(rbase + j) * N + col] = f2bf(acc[mi][ni][j] + bv);
                } else {
                    const int bb = rbase >> 11;
                    const int seq = rbase & 2047;
                    const int d = col - 2048;
                    ushort4 pk;
                    pk.x = f2bf(acc[mi][ni][0] + bv);
                    pk.y = f2bf(acc[mi][ni][1] + bv);
                    pk.z = f2bf(acc[mi][ni][2] + bv);
                    pk.w = f2bf(acc[mi][ni][3] + bv);
                    *(ushort4*)&Vt[(size_t)bb * 2097152 + (size_t)d * 2048 + seq] = pk;
                }
            }
        }
}

// ---------------------------------------------------------------------------
// MFMA flash attention v16 (R14, RESTORED): 8-wave blocks, QBLK=128, no
// split-K, XCD remap, rotating 2-buffer prefetch (tile tt+2 issued after
// barrier ending tt), raw v_exp_f32, pre-folded scale, setprio.
// R15's 4-buffer variant was FLAT (47.7us both) -> barrier count is not
// the binding term; keep the simpler 2-buffer form. Attn parked at 47.7us
// (remaining stall is the per-wave serial chain; restructure = T12/T16,
// too risky this late).
// ---------------------------------------------------------------------------
__global__ __launch_bounds__(512, 4) void attn_fwd_mfma(
    const ushort* __restrict__ qkv, const ushort* __restrict__ Vt,
    ushort* __restrict__ ctx) {
    const int L = blockIdx.x;             // [0,512)
    const int xcd = L & 7, slot = L >> 3; // slot in [0,64)
    const int g = xcd * 4 + (slot >> 4);  // (b,h) group; 4 groups per XCD
    const int qb = slot & 15;             // 128-row Q block within (b,h)
    const int b = g >> 4, h = g & 15;
    const int tid = threadIdx.x;          // [0,512)
    const int wid = tid >> 6, lane = tid & 63, quad = lane >> 4, l16 = lane & 15;
    const int wq = wid * 16;              // wave owns rows [wq, wq+16)
    const int r7 = l16 & 7;

    __shared__ ushort Ks[2][64 * 64];    // [kpos][d], swizzled chunks
    __shared__ ushort Vts[2][64 * 64];   // [d][kpos], swizzled chunks
    __shared__ ushort Ps[128 * 64];      // prologue: Q tile; loop: [qrow][kpos]

    // stage helper pattern: 512 threads, 1 chunk each for K and V;
    // LDS slot = lane order, source chunk j^(r&7).
    const int sr = tid >> 3;
    const int skc = (tid & 7) ^ (sr & 7);

    // async stage Q tile (128 rows = 1024 chunks, 512 threads, 2 reps)
#pragma unroll
    for (int rep = 0; rep < 2; ++rep) {
        int c = tid + rep * 512;
        int r = c >> 3;
        int kc = (c & 7) ^ (r & 7);
        ushort* lb = &Ps[(rep * 512 + wid * 64) * 8];   // wave-uniform base
        __builtin_amdgcn_global_load_lds(
            AS1U(qkv + (size_t)(b * 2048 + qb * 128 + r) * 3072 + h * 64 + kc * 8),
            AS3U(lb), 16, 0, 0);
    }
    // prologue: stage tiles 0 and 1 into buf 0 and 1
#pragma unroll
    for (int kt = 0; kt < 2; ++kt) {
        ushort* lbK = &Ks[kt][(wid * 64) * 8];
        ushort* lbV = &Vts[kt][(wid * 64) * 8];
        __builtin_amdgcn_global_load_lds(
            AS1U(qkv + (size_t)(b * 2048 + kt * 64 + sr) * 3072 + 1024 + h * 64 + skc * 8),
            AS3U(lbK), 16, 0, 0);
        __builtin_amdgcn_global_load_lds(
            AS1U(Vt + (size_t)b * 2097152 + (size_t)(h * 64 + sr) * 2048 + kt * 64 + skc * 8),
            AS3U(lbV), 16, 0, 0);
    }
    __syncthreads();   // Q + tiles 0,1 visible to all waves

    // hoist Q fragments to registers: tile-invariant across all KV tiles.
    s16x8 qreg[2];
#pragma unroll
    for (int ks = 0; ks < 2; ++ks) {
        const int slot2 = ((ks * 4 + quad) ^ r7) * 8;
        qreg[ks] = *(const s16x8*)&Ps[(wq + l16) * 64 + slot2];
    }

    f32x4 o[4] = {};
    float l_r = 0.f;

    for (int tt = 0; tt < 32; ++tt) {
        const int buf = tt & 1;

        // ---- compute tile tt from buf ----
        f32x4 s[4] = {};
        __builtin_amdgcn_s_setprio(1);
#pragma unroll
        for (int ks = 0; ks < 2; ++ks) {
            const int slot2 = ((ks * 4 + quad) ^ r7) * 8;
            s16x8 ka[4];
#pragma unroll
            for (int mi = 0; mi < 4; ++mi)
                ka[mi] = *(const s16x8*)&Ks[buf][(mi * 16 + l16) * 64 + slot2];
#pragma unroll
            for (int mi = 0; mi < 4; ++mi)
                s[mi] = __builtin_amdgcn_mfma_f32_16x16x32_bf16(
                    ka[mi], qreg[ks], s[mi], 0, 0, 0);
        }
        __builtin_amdgcn_s_setprio(0);

        // P write: kpos chunk jq = 2*mi + (quad>>1), sub-offset (quad&1)*4
#pragma unroll
        for (int mi = 0; mi < 4; ++mi) {
            ushort4 pk;
#pragma unroll
            for (int j = 0; j < 4; ++j) {
                float p = __builtin_amdgcn_exp2f(s[mi][j]);  // raw v_exp_f32
                l_r += p;
                ((ushort*)&pk)[j] = f2bf(p);
            }
            const int jq = 2 * mi + (quad >> 1);
            *(ushort4*)&Ps[(wq + l16) * 64 + ((jq ^ r7)) * 8 + (quad & 1) * 4] = pk;
        }

        __builtin_amdgcn_s_setprio(1);
#pragma unroll
        for (int ks = 0; ks < 2; ++ks) {
            const int slot2 = ((ks * 4 + quad) ^ r7) * 8;
            s16x8 va[4], pb;
#pragma unroll
            for (int md = 0; md < 4; ++md)
                va[md] = *(const s16x8*)&Vts[buf][(md * 16 + l16) * 64 + slot2];
            pb = *(const s16x8*)&Ps[(wq + l16) * 64 + slot2];
#pragma unroll
            for (int md = 0; md < 4; ++md)
                o[md] = __builtin_amdgcn_mfma_f32_16x16x32_bf16(
                    va[md], pb, o[md], 0, 0, 0);
        }
        __builtin_amdgcn_s_setprio(0);

        // ---- barrier: all waves done reading buf; drains tile tt+1's
        //      loads (issued one full compute phase ago) ----
        __syncthreads();

        // ---- issue tile tt+2's loads into buf (flies through compute
        //      of tile tt+1; drained by the NEXT barrier) ----
        if (tt + 2 < 32) {
            const int kt = tt + 2;
            ushort* lbK = &Ks[buf][(wid * 64) * 8];
            ushort* lbV = &Vts[buf][(wid * 64) * 8];
            __builtin_amdgcn_global_load_lds(
                AS1U(qkv + (size_t)(b * 2048 + kt * 64 + sr) * 3072 + 1024 + h * 64 + skc * 8),
                AS3U(lbK), 16, 0, 0);
            __builtin_amdgcn_global_load_lds(
                AS1U(Vt + (size_t)b * 2097152 + (size_t)(h * 64 + sr) * 2048 + kt * 64 + skc * 8),
                AS3U(lbV), 16, 0, 0);
        }
    }

    // epilogue: reduce l across quads, normalize, write ctx directly.
    float l = l_r;
    l += __shfl_xor(l, 16);
    l += __shfl_xor(l, 32);
    const float inv = 1.f / l;
    const size_t row = (size_t)(b * 2048 + qb * 128 + wq + l16);
#pragma unroll
    for (int md = 0; md < 4; ++md) {
        ushort4 pk;
#pragma unroll
        for (int j = 0; j < 4; ++j)
            ((ushort*)&pk)[j] = f2bf(o[md][j] * inv);
        *(ushort4*)&ctx[row * 1024 + h * 64 + md * 16 + quad * 4] = pk;
    }
}

// ---------------------------------------------------------------------------
// Workspace layout (MB offsets), total 78 MB:
//   [0,16M)   A0  } reused: qkv bf16 [0,24M), Vt [24M,32M), ctx [32M,40M)
//   [16M,32M) A1  }
//   [32M,49M) H_a } dead after FFT -> ctx reuses [32M,40M)
//   [49M,54M) H_p
//   [54M,58M) P0   [58M,62M) P1
//   [62M,68M) WaT  [68M,70M) WpT  [70M,78M) x_bf
// ---------------------------------------------------------------------------
extern "C" void kernel_launch(void* const* d_in, const int* in_sizes, int n_in,
                              void* d_out, int out_size, void* d_ws, size_t ws_size,
                              hipStream_t stream) {
    const float* x        = (const float*)d_in[0];
    const float* attn_re  = (const float*)d_in[1];
    const float* attn_im  = (const float*)d_in[2];
    const int*   attn_idx = (const int*)d_in[3];
    const float* attn_sc  = (const float*)d_in[4];
    const float* proj_re  = (const float*)d_in[5];
    const float* proj_im  = (const float*)d_in[6];
    const int*   proj_idx = (const int*)d_in[7];
    const float* proj_sc  = (const float*)d_in[8];
    const float* attn_b   = (const float*)d_in[9];
    const float* proj_b   = (const float*)d_in[10];
    float* out = (float*)d_out;

    const size_t MB = 1048576;
    char* w = (char*)d_ws;
    float2* A0  = (float2*)(w);
    float2* A1  = (float2*)(w + 16 * MB);
    float2* Ha  = (float2*)(w + 32 * MB);
    float2* Hp  = (float2*)(w + 49 * MB);
    float2* P0  = (float2*)(w + 54 * MB);
    float2* P1  = (float2*)(w + 58 * MB);
    ushort* WaT = (ushort*)(w + 62 * MB);
    ushort* WpT = (ushort*)(w + 68 * MB);
    ushort* x_bf= (ushort*)(w + 70 * MB);
    ushort* qkvb= (ushort*)(w);
    ushort* Vt  = (ushort*)(w + 24 * MB);
    ushort* ctx = (ushort*)(w + 32 * MB);

    // one memset covers Ha [32M,~48.8M) and Hp [49M,~53.2M) (gap is dead)
    hipMemsetAsync(w + 32 * MB, 0, 22 * MB, stream);

    // x->bf16 ∥ scatter (after memset: scatter writes into Ha/Hp)
    x_scatter<<<6656, 256, 0, stream>>>(
        x, x_bf, attn_re, attn_im, attn_idx, Ha, proj_re, proj_im, proj_idx, Hp);

    // FUSED stage 1 (pack + first butterfly), both chains: Ha->A1, Hp->P1
    // threv = 1/PAD (exact pow2): pack twiddles in REVOLUTIONS.
    fft_pack1<<<2048, 256, 0, stream>>>(
        Ha, A1, (float)(1.0 / ATTN_PAD_C), 1024,
        Hp, P1, (float)(1.0 / PROJ_PAD_C), PROJ_NC / 2, PROJ_NC / 2);

    // remaining paired iFFT stages
    fft_r64_dual<<<1280, 256, 0, stream>>>(A1, A0, 6,  ATTN_NC >> 9,  1024,
                                           P1, P0, 1,  PROJ_NC >> 4);
    fft_r64_dual<<<1280, 256, 0, stream>>>(A0, A1, 12, ATTN_NC >> 15, 1024,
                                           P0, P1, 7,  PROJ_NC >> 10);
    fft_r8_r64 <<<1280, 256, 0, stream>>>(A1, A0, 18, 0.125f,   // rev = p/8
                                          ATTN_NC / 8, 1024,
                                          P1, P0, 13, PROJ_NC >> 16);
    // transpose both weight matrices
    transpose_dual<<<4096, 256, 0, stream>>>(A0, WaT, attn_sc, P0, WpT, proj_sc);

    // qkv = x @ Wa + bias (bf16 out; V third written transposed into Vt)
    gemm_bt_mfma<1><<<dim3(3072 / 128, 4096 / 128), 256, 0, stream>>>(
        x_bf, WaT, attn_b, qkvb, Vt, 4096, 3072, 1024);

    // attention: 8-wave blocks, rotating prefetch, XCD remap, ctx out
    attn_fwd_mfma<<<512, 512, 0, stream>>>(qkvb, Vt, ctx);

    gemm_bt_mfma<0><<<dim3(1024 / 128, 4096 / 128), 256, 0, stream>>>(
        ctx, WpT, proj_b, out, (ushort*)nullptr, 4096, 1024, 1024);
}

// Round 17
// 241.231 us; speedup vs baseline: 1.0499x; 1.0499x over previous
//
#include <hip/hip_runtime.h>
#include <math.h>

#define N_HEADC  16
#define D_MODELC 1024
#define ATTN_N_C    3145728
#define ATTN_PAD_C  4194304
#define ATTN_NC     2097152   // half-size complex FFT length (2^21 = 8^7)
#define ATTN_KEEP_C 524288
#define PROJ_N_C    1048576
#define PROJ_PAD_C  1048576
#define PROJ_NC     524288    // 2^19 = 2 * 8^6
#define PROJ_KEEP_C 131072
#define BATCH_C 2
#define SEQ_C   2048

// 0.125 * log2(e): folded into Wa's Q-columns + Q-bias so attn does exp2(s)
#define CEXP_C 0.18033688011112042f

typedef __attribute__((ext_vector_type(8))) short s16x8;
typedef __attribute__((ext_vector_type(4))) float f32x4;

#define AS1U(p) ((const __attribute__((address_space(1))) uint*)(p))
#define AS3U(p) ((__attribute__((address_space(3))) uint*)(p))

static __device__ __forceinline__ ushort f2bf(float f) {
    __bf16 b = (__bf16)f;
    return __builtin_bit_cast(ushort, b);
}
static __device__ __forceinline__ float bf2f(ushort u) {
    return __builtin_bit_cast(float, ((uint)u) << 16);
}
static __device__ __forceinline__ float2 cmul(float2 a, float2 b) {
    return make_float2(a.x * b.x - a.y * b.y, a.x * b.y + a.y * b.x);
}
static __device__ __forceinline__ float2 cadd(float2 a, float2 b) {
    return make_float2(a.x + b.x, a.y + b.y);
}
static __device__ __forceinline__ float2 csub(float2 a, float2 b) {
    return make_float2(a.x - b.x, a.y - b.y);
}
static __device__ __forceinline__ float2 crot(float2 z) {   // i*z
    return make_float2(-z.y, z.x);
}

// 8-point inverse DFT core (verified R9). a[0..7] -> B[0..7] (pre-twiddle).
static __device__ __forceinline__ void r8core(const float2* a, float2* B) {
    const float2 t0 = cadd(a[0], a[4]), t1 = csub(a[0], a[4]);
    const float2 t2 = cadd(a[2], a[6]), t3 = csub(a[2], a[6]);
    const float2 t4 = cadd(a[1], a[5]), t5 = csub(a[1], a[5]);
    const float2 t6 = cadd(a[3], a[7]), t7 = csub(a[3], a[7]);
    const float2 E0 = cadd(t0, t2), E2 = csub(t0, t2);
    const float2 E1 = cadd(t1, crot(t3)), E3 = csub(t1, crot(t3));
    const float2 F0 = cadd(t4, t6), F2 = csub(t4, t6);
    const float2 F1 = cadd(t5, crot(t7)), F3 = csub(t5, crot(t7));
    const float c = 0.70710678118654752f;
    const float2 G1 = make_float2(c * (F1.x - F1.y), c * (F1.x + F1.y));   // c(1+i)F1
    const float2 G2 = crot(F2);                                            // iF2
    const float2 G3 = make_float2(c * (-F3.x - F3.y), c * (F3.x - F3.y));  // c(-1+i)F3
    B[0] = cadd(E0, F0); B[4] = csub(E0, F0);
    B[1] = cadd(E1, G1); B[5] = csub(E1, G1);
    B[2] = cadd(E2, G2); B[6] = csub(E2, G2);
    B[3] = cadd(E3, G3); B[7] = csub(E3, G3);
}

// ---------------------------------------------------------------------------
// R32 FINAL: exact R14 configuration restored (best measured: 245.6us).
// R16's sincos-revolutions experiment fired its revert trigger (+7.7us
// total; OCML __sincosf shares one reduction across sin+cos so the saving
// was mis-modeled). Session summary of kept wins: BK=64 GEMM (R4), attn
// XCD-locality remap (R5, FETCH 41->12MB), launch merges 19->9 (R6/R8),
// no-split-K (R9, -40MB glue), 8-wave blocks (R12), rotating prefetch
// (R13), raw v_exp_f32 (R14, -25% attn), scale pre-fold (R3).
// ---------------------------------------------------------------------------

static __device__ __forceinline__ float2 pack_eval(
    const float2* __restrict__ H, int Nc, float th0, int k) {
    float2 g = H[k];
    float2 hm = H[Nc - k];
    if (k == 0) { g.y = 0.f; hm.y = 0.f; }
    float2 gh = make_float2(hm.x, -hm.y);
    float2 sum = make_float2(g.x + gh.x, g.y + gh.y);
    float2 dif = make_float2(g.x - gh.x, g.y - gh.y);
    float si, co;
    __sincosf(th0 * (float)k, &si, &co);
    float2 t = make_float2(dif.x * co - dif.y * si, dif.x * si + dif.y * co);
    return make_float2(sum.x - t.y, sum.y + t.x);
}

static __device__ __forceinline__ void r2_body(
    const float2* __restrict__ in, float2* __restrict__ out,
    int slog, int m, int half, int t) {
    if (t >= half) return;
    int s = 1 << slog;
    int q = t & (s - 1);
    int p = t >> slog;
    float si, co;
    __sincosf((float)(M_PI / (double)m) * (float)p, &si, &co);
    float2 a = in[q + s * p];
    float2 b = in[q + s * (p + m)];
    float2 su = cadd(a, b);
    float2 di = csub(a, b);
    int ob = q + ((s << 1) * p);
    out[ob]     = su;
    out[ob + s] = make_float2(di.x * co - di.y * si, di.x * si + di.y * co);
}

// proj stage 1: radix-2 peel with pack fused (slog=0: reads elements t, t+m)
static __device__ __forceinline__ void r2_pack_body(
    const float2* __restrict__ H, float2* __restrict__ out,
    int Nc, float th0, int m, int half, int t) {
    if (t >= half) return;
    float2 a = pack_eval(H, Nc, th0, t);
    float2 b = pack_eval(H, Nc, th0, t + m);
    float si, co;
    __sincosf((float)(M_PI / (double)m) * (float)t, &si, &co);
    float2 su = cadd(a, b);
    float2 di = csub(a, b);
    out[2 * t]     = su;
    out[2 * t + 1] = make_float2(di.x * co - di.y * si, di.x * si + di.y * co);
}

static __device__ __forceinline__ void r8_body(
    const float2* __restrict__ in, float2* __restrict__ out,
    int slog, int M, float ang0, int eighth, int t) {
    if (t >= eighth) return;
    const int s = 1 << slog;
    const int q = t & (s - 1);
    const int p = t >> slog;
    float2 a[8];
#pragma unroll
    for (int j = 0; j < 8; ++j)
        a[j] = in[q + (size_t)s * (p + j * M)];
    float2 B[8];
    r8core(a, B);
    float si, co;
    __sincosf(ang0 * (float)p, &si, &co);
    const float2 w = make_float2(co, si);
    const int ob = q + 8 * s * p;
    out[ob] = B[0];
    float2 wj = w;
    out[ob + s] = cmul(wj, B[1]);
#pragma unroll
    for (int j = 2; j < 8; ++j) {
        wj = cmul(wj, w);
        out[ob + j * s] = cmul(wj, B[j]);
    }
}

static __device__ void r64_body(
    float2 (*Ysh)[8][9],
    const float2* __restrict__ in, float2* __restrict__ out,
    int slog, int M, int vb) {
    const int tid = threadIdx.x;
    const int g = tid & 31, u = tid >> 5;
    const int s = 1 << slog;
    const int M8 = M >> 3;
    const int G = vb * 32 + g;
    const int q = G & (s - 1);
    const int p0 = G >> slog;

    const int p = p0 + u * M8;
    float2 a[8];
#pragma unroll
    for (int j = 0; j < 8; ++j)
        a[j] = in[q + (size_t)s * (p + j * M)];
    float2 B[8];
    r8core(a, B);
    float si, co;
    __sincosf((0.78539816339744831f / (float)M) * (float)p, &si, &co);  // pi/(4M)*p
    const float2 w = make_float2(co, si);
    Ysh[g][u][0] = B[0];
    float2 wj = w;
    Ysh[g][u][1] = cmul(wj, B[1]);
#pragma unroll
    for (int j = 2; j < 8; ++j) {
        wj = cmul(wj, w);
        Ysh[g][u][j] = cmul(wj, B[j]);
    }
    __syncthreads();

    float2 z[8];
#pragma unroll
    for (int jp = 0; jp < 8; ++jp)
        z[jp] = Ysh[g][jp][u];
    float2 B2[8];
    r8core(z, B2);
    __sincosf((0.78539816339744831f / (float)M8) * (float)p0, &si, &co); // pi/(4*M8)*p0
    const float2 w2 = make_float2(co, si);
    const size_t ob = (size_t)q + (size_t)u * s + (size_t)64 * s * p0;
    out[ob] = B2[0];
    float2 wj2 = w2;
    out[ob + (size_t)8 * s] = cmul(wj2, B2[1]);
#pragma unroll
    for (int j2 = 2; j2 < 8; ++j2) {
        wj2 = cmul(wj2, w2);
        out[ob + (size_t)j2 * 8 * s] = cmul(wj2, B2[j2]);
    }
}

// attn stage 1: radix-64 with pack fused (slog=0: s=1, q=0, element p+jM)
static __device__ void r64_pack_body(
    float2 (*Ysh)[8][9],
    const float2* __restrict__ H, float2* __restrict__ out,
    int Nc, float th0, int M, int vb) {
    const int tid = threadIdx.x;
    const int g = tid & 31, u = tid >> 5;
    const int M8 = M >> 3;
    const int p0 = vb * 32 + g;
    const int p = p0 + u * M8;
    float2 a[8];
#pragma unroll
    for (int j = 0; j < 8; ++j)
        a[j] = pack_eval(H, Nc, th0, p + j * M);
    float2 B[8];
    r8core(a, B);
    float si, co;
    __sincosf((0.78539816339744831f / (float)M) * (float)p, &si, &co);  // pi/(4M)*p
    const float2 w = make_float2(co, si);
    Ysh[g][u][0] = B[0];
    float2 wj = w;
    Ysh[g][u][1] = cmul(wj, B[1]);
#pragma unroll
    for (int j = 2; j < 8; ++j) {
        wj = cmul(wj, w);
        Ysh[g][u][j] = cmul(wj, B[j]);
    }
    __syncthreads();

    float2 z[8];
#pragma unroll
    for (int jp = 0; jp < 8; ++jp)
        z[jp] = Ysh[g][jp][u];
    float2 B2[8];
    r8core(z, B2);
    __sincosf((0.78539816339744831f / (float)M8) * (float)p0, &si, &co); // pi/(4*M8)*p0
    const float2 w2 = make_float2(co, si);
    const size_t ob = (size_t)u + (size_t)64 * p0;
    out[ob] = B2[0];
    float2 wj2 = w2;
    out[ob + 8] = cmul(wj2, B2[1]);
#pragma unroll
    for (int j2 = 2; j2 < 8; ++j2) {
        wj2 = cmul(wj2, w2);
        out[ob + (size_t)j2 * 8] = cmul(wj2, B2[j2]);
    }
}

static __device__ __forceinline__ void transpose_body(
    float (*T)[33], const float2* __restrict__ z, ushort* __restrict__ WT,
    int Kd, int Nd, float inv, const float* __restrict__ sc, int qcols, int vb) {
    const int nbx = Nd >> 5;
    const int n0 = (vb % nbx) * 32, k0 = (vb / nbx) * 32;
    const int tx = threadIdx.x & 31, ty = threadIdx.x >> 5;
    const float s = inv * sc[0];
    for (int r = ty; r < 32; r += 8) {
        size_t j = (size_t)(k0 + r) * Nd + n0 + tx;
        float2 zz = z[j >> 1];
        T[r][tx] = (j & 1) ? zz.y : zz.x;
    }
    __syncthreads();
    for (int r = ty; r < 32; r += 8) {
        const float fs = ((n0 + r) < qcols) ? s * CEXP_C : s;
        WT[(size_t)(n0 + r) * Kd + k0 + tx] = f2bf(T[tx][r] * fs);
    }
}

// ---- merged dispatch kernels ----

// x->bf16 (4096 blocks) ∥ spectral scatter (2560 blocks)
__global__ __launch_bounds__(256) void x_scatter(
    const float* __restrict__ x, ushort* __restrict__ xb,
    const float* __restrict__ re_a, const float* __restrict__ im_a,
    const int* __restrict__ idx_a, float2* __restrict__ Ha,
    const float* __restrict__ re_p, const float* __restrict__ im_p,
    const int* __restrict__ idx_p, float2* __restrict__ Hp) {
    const int B = blockIdx.x;
    if (B < 4096) {
        const int i = B * 256 + threadIdx.x;
        float4 v = *(const float4*)(x + (size_t)i * 4);
        ushort4 o;
        o.x = f2bf(v.x); o.y = f2bf(v.y); o.z = f2bf(v.z); o.w = f2bf(v.w);
        *(ushort4*)(xb + (size_t)i * 4) = o;
    } else {
        const int t = (B - 4096) * 256 + threadIdx.x;
        if (t < ATTN_KEEP_C) {
            Ha[idx_a[t]] = make_float2(re_a[t], im_a[t]);
        } else {
            const int u = t - ATTN_KEEP_C;
            Hp[idx_p[u]] = make_float2(re_p[u], im_p[u]);
        }
    }
}

// FUSED stage 1: attn pack+r64 (1024 blocks) ∥ proj pack+r2 (1024 blocks)
__global__ __launch_bounds__(256) void fft_pack1(
    const float2* __restrict__ Ha, float2* __restrict__ oa, float tha, int na,
    const float2* __restrict__ Hp, float2* __restrict__ op, float thp,
    int mp, int halfp) {
    __shared__ float2 Ysh[32][8][9];
    if ((int)blockIdx.x < na)
        r64_pack_body(Ysh, Ha, oa, ATTN_NC, tha, ATTN_NC >> 3, blockIdx.x);
    else
        r2_pack_body(Hp, op, PROJ_NC, thp, mp, halfp,
                     (blockIdx.x - na) * 256 + threadIdx.x);
}

// attn r64 ∥ proj r64
__global__ __launch_bounds__(256) void fft_r64_dual(
    const float2* __restrict__ ia, float2* __restrict__ oa, int sla, int Ma, int na,
    const float2* __restrict__ ip, float2* __restrict__ op, int slp, int Mp) {
    __shared__ float2 Ysh[32][8][9];
    if ((int)blockIdx.x < na)
        r64_body(Ysh, ia, oa, sla, Ma, blockIdx.x);
    else
        r64_body(Ysh, ip, op, slp, Mp, blockIdx.x - na);
}

// attn r8 final ∥ proj r64 final
__global__ __launch_bounds__(256) void fft_r8_r64(
    const float2* __restrict__ ia, float2* __restrict__ oa, int sla, float ang0,
    int eighth, int na,
    const float2* __restrict__ ip, float2* __restrict__ op, int slp, int Mp) {
    __shared__ float2 Ysh[32][8][9];
    if ((int)blockIdx.x < na)
        r8_body(ia, oa, sla, 1, ang0, eighth, (blockIdx.x) * 256 + threadIdx.x);
    else
        r64_body(Ysh, ip, op, slp, Mp, blockIdx.x - na);
}

// transpose attn (3072 tiles) ∥ transpose proj (1024 tiles)
__global__ __launch_bounds__(256) void transpose_dual(
    const float2* __restrict__ za, ushort* __restrict__ Wa, const float* __restrict__ sca,
    const float2* __restrict__ zp, ushort* __restrict__ Wp, const float* __restrict__ scp) {
    __shared__ float T[32][33];
    if (blockIdx.x < 3072)
        transpose_body(T, za, Wa, 1024, 3072, 1.f / ATTN_PAD_C, sca, 1024, blockIdx.x);
    else
        transpose_body(T, zp, Wp, 1024, 1024, 1.f / PROJ_PAD_C, scp, 0, blockIdx.x - 3072);
}

// ---------------------------------------------------------------------------
// bf16 MFMA GEMM v5 (R21): BK=64 + 2-D grid (default mapping already puts
// all 32 B-panel sharers on one XCD). OUTMODE==1: Q-bias fold.
// ---------------------------------------------------------------------------
template <int OUTMODE>
__global__ __launch_bounds__(256) void gemm_bt_mfma(
    const ushort* __restrict__ A, const ushort* __restrict__ Bt,
    const float* __restrict__ bias, void* __restrict__ Cout,
    ushort* __restrict__ Vt, int M, int N, int K) {
    __shared__ ushort As[128 * 64];
    __shared__ ushort Bs[128 * 64];
    const int tid = threadIdx.x;
    const int wid = tid >> 6, lane = tid & 63, quad = lane >> 4, l16 = lane & 15;
    const int row0 = blockIdx.y * 128, col0 = blockIdx.x * 128;
    const int mh = (wid >> 1) * 64, nh = (wid & 1) * 64;
    const int r7 = l16 & 7;

    f32x4 acc[4][4] = {};

    for (int k0 = 0; k0 < K; k0 += 64) {
        __syncthreads();
#pragma unroll
        for (int rep = 0; rep < 4; ++rep) {
            int c = tid + rep * 256;
            int r = c >> 3;
            int kc = (c & 7) ^ (r & 7);
            ushort* lbA = &As[(rep * 256 + wid * 64) * 8];
            ushort* lbB = &Bs[(rep * 256 + wid * 64) * 8];
            __builtin_amdgcn_global_load_lds(
                AS1U(A + (size_t)(row0 + r) * K + k0 + kc * 8), AS3U(lbA), 16, 0, 0);
            __builtin_amdgcn_global_load_lds(
                AS1U(Bt + (size_t)(col0 + r) * K + k0 + kc * 8), AS3U(lbB), 16, 0, 0);
        }
        __syncthreads();
#pragma unroll
        for (int kk = 0; kk < 2; ++kk) {
            const int slot = ((kk * 4 + quad) ^ r7) * 8;
            s16x8 af[4], bfr[4];
#pragma unroll
            for (int mi = 0; mi < 4; ++mi)
                af[mi] = *(const s16x8*)&As[(mh + mi * 16 + l16) * 64 + slot];
#pragma unroll
            for (int ni = 0; ni < 4; ++ni)
                bfr[ni] = *(const s16x8*)&Bs[(nh + ni * 16 + l16) * 64 + slot];
#pragma unroll
            for (int mi = 0; mi < 4; ++mi)
#pragma unroll
                for (int ni = 0; ni < 4; ++ni)
                    acc[mi][ni] = __builtin_amdgcn_mfma_f32_16x16x32_bf16(
                        af[mi], bfr[ni], acc[mi][ni], 0, 0, 0);
        }
    }

#pragma unroll
    for (int mi = 0; mi < 4; ++mi)
#pragma unroll
        for (int ni = 0; ni < 4; ++ni) {
            const int col = col0 + nh + ni * 16 + l16;
            const int rbase = row0 + mh + mi * 16 + quad * 4;
            float bv = bias[col];
            if (OUTMODE == 1 && col < 1024) bv *= CEXP_C;   // Q-bias fold
            if (OUTMODE == 0) {
                float* C = (float*)Cout;
#pragma unroll
                for (int j = 0; j < 4; ++j)
                    C[(size_t)(rbase + j) * N + col] = acc[mi][ni][j] + bv;
            } else {
                if (col < 2048) {
                    ushort* C = (ushort*)Cout;
#pragma unroll
                    for (int j = 0; j < 4; ++j)
                        C[(size_t)(rbase + j) * N + col] = f2bf(acc[mi][ni][j] + bv);
                } else {
                    const int bb = rbase >> 11;
                    const int seq = rbase & 2047;
                    const int d = col - 2048;
                    ushort4 pk;
                    pk.x = f2bf(acc[mi][ni][0] + bv);
                    pk.y = f2bf(acc[mi][ni][1] + bv);
                    pk.z = f2bf(acc[mi][ni][2] + bv);
                    pk.w = f2bf(acc[mi][ni][3] + bv);
                    *(ushort4*)&Vt[(size_t)bb * 2097152 + (size_t)d * 2048 + seq] = pk;
                }
            }
        }
}

// ---------------------------------------------------------------------------
// MFMA flash attention v16 (R14, FINAL): 8-wave blocks (512 thr, wave w
// owns Q-rows [w*16,w*16+16)), QBLK=128, no split-K (normalized ctx out),
// XCD-locality remap (FETCH 41->12MB), rotating 2-buffer prefetch (tile
// tt+2 issued after the barrier ending tt -> full compute phase of
// flight), raw v_exp_f32 softmax (scale pre-folded into Wa/bias), setprio
// around MFMA clusters. Measured 47.7us (from 76.7 at session start).
// ---------------------------------------------------------------------------
__global__ __launch_bounds__(512, 4) void attn_fwd_mfma(
    const ushort* __restrict__ qkv, const ushort* __restrict__ Vt,
    ushort* __restrict__ ctx) {
    const int L = blockIdx.x;             // [0,512)
    const int xcd = L & 7, slot = L >> 3; // slot in [0,64)
    const int g = xcd * 4 + (slot >> 4);  // (b,h) group; 4 groups per XCD
    const int qb = slot & 15;             // 128-row Q block within (b,h)
    const int b = g >> 4, h = g & 15;
    const int tid = threadIdx.x;          // [0,512)
    const int wid = tid >> 6, lane = tid & 63, quad = lane >> 4, l16 = lane & 15;
    const int wq = wid * 16;              // wave owns rows [wq, wq+16)
    const int r7 = l16 & 7;

    __shared__ ushort Ks[2][64 * 64];    // [kpos][d], swizzled chunks
    __shared__ ushort Vts[2][64 * 64];   // [d][kpos], swizzled chunks
    __shared__ ushort Ps[128 * 64];      // prologue: Q tile; loop: [qrow][kpos]

    // stage helper pattern: 512 threads, 1 chunk each for K and V;
    // LDS slot = lane order, source chunk j^(r&7).
    const int sr = tid >> 3;
    const int skc = (tid & 7) ^ (sr & 7);

    // async stage Q tile (128 rows = 1024 chunks, 512 threads, 2 reps)
#pragma unroll
    for (int rep = 0; rep < 2; ++rep) {
        int c = tid + rep * 512;
        int r = c >> 3;
        int kc = (c & 7) ^ (r & 7);
        ushort* lb = &Ps[(rep * 512 + wid * 64) * 8];   // wave-uniform base
        __builtin_amdgcn_global_load_lds(
            AS1U(qkv + (size_t)(b * 2048 + qb * 128 + r) * 3072 + h * 64 + kc * 8),
            AS3U(lb), 16, 0, 0);
    }
    // prologue: stage tiles 0 and 1 into buf 0 and 1
#pragma unroll
    for (int kt = 0; kt < 2; ++kt) {
        ushort* lbK = &Ks[kt][(wid * 64) * 8];
        ushort* lbV = &Vts[kt][(wid * 64) * 8];
        __builtin_amdgcn_global_load_lds(
            AS1U(qkv + (size_t)(b * 2048 + kt * 64 + sr) * 3072 + 1024 + h * 64 + skc * 8),
            AS3U(lbK), 16, 0, 0);
        __builtin_amdgcn_global_load_lds(
            AS1U(Vt + (size_t)b * 2097152 + (size_t)(h * 64 + sr) * 2048 + kt * 64 + skc * 8),
            AS3U(lbV), 16, 0, 0);
    }
    __syncthreads();   // Q + tiles 0,1 visible to all waves

    // hoist Q fragments to registers: tile-invariant across all KV tiles.
    s16x8 qreg[2];
#pragma unroll
    for (int ks = 0; ks < 2; ++ks) {
        const int slot2 = ((ks * 4 + quad) ^ r7) * 8;
        qreg[ks] = *(const s16x8*)&Ps[(wq + l16) * 64 + slot2];
    }

    f32x4 o[4] = {};
    float l_r = 0.f;

    for (int tt = 0; tt < 32; ++tt) {
        const int buf = tt & 1;

        // ---- compute tile tt from buf ----
        f32x4 s[4] = {};
        __builtin_amdgcn_s_setprio(1);
#pragma unroll
        for (int ks = 0; ks < 2; ++ks) {
            const int slot2 = ((ks * 4 + quad) ^ r7) * 8;
            s16x8 ka[4];
#pragma unroll
            for (int mi = 0; mi < 4; ++mi)
                ka[mi] = *(const s16x8*)&Ks[buf][(mi * 16 + l16) * 64 + slot2];
#pragma unroll
            for (int mi = 0; mi < 4; ++mi)
                s[mi] = __builtin_amdgcn_mfma_f32_16x16x32_bf16(
                    ka[mi], qreg[ks], s[mi], 0, 0, 0);
        }
        __builtin_amdgcn_s_setprio(0);

        // P write: kpos chunk jq = 2*mi + (quad>>1), sub-offset (quad&1)*4
#pragma unroll
        for (int mi = 0; mi < 4; ++mi) {
            ushort4 pk;
#pragma unroll
            for (int j = 0; j < 4; ++j) {
                float p = __builtin_amdgcn_exp2f(s[mi][j]);  // raw v_exp_f32
                l_r += p;
                ((ushort*)&pk)[j] = f2bf(p);
            }
            const int jq = 2 * mi + (quad >> 1);
            *(ushort4*)&Ps[(wq + l16) * 64 + ((jq ^ r7)) * 8 + (quad & 1) * 4] = pk;
        }

        __builtin_amdgcn_s_setprio(1);
#pragma unroll
        for (int ks = 0; ks < 2; ++ks) {
            const int slot2 = ((ks * 4 + quad) ^ r7) * 8;
            s16x8 va[4], pb;
#pragma unroll
            for (int md = 0; md < 4; ++md)
                va[md] = *(const s16x8*)&Vts[buf][(md * 16 + l16) * 64 + slot2];
            pb = *(const s16x8*)&Ps[(wq + l16) * 64 + slot2];
#pragma unroll
            for (int md = 0; md < 4; ++md)
                o[md] = __builtin_amdgcn_mfma_f32_16x16x32_bf16(
                    va[md], pb, o[md], 0, 0, 0);
        }
        __builtin_amdgcn_s_setprio(0);

        // ---- barrier: all waves done reading buf; drains tile tt+1's
        //      loads (issued one full compute phase ago) ----
        __syncthreads();

        // ---- issue tile tt+2's loads into buf (flies through compute
        //      of tile tt+1; drained by the NEXT barrier) ----
        if (tt + 2 < 32) {
            const int kt = tt + 2;
            ushort* lbK = &Ks[buf][(wid * 64) * 8];
            ushort* lbV = &Vts[buf][(wid * 64) * 8];
            __builtin_amdgcn_global_load_lds(
                AS1U(qkv + (size_t)(b * 2048 + kt * 64 + sr) * 3072 + 1024 + h * 64 + skc * 8),
                AS3U(lbK), 16, 0, 0);
            __builtin_amdgcn_global_load_lds(
                AS1U(Vt + (size_t)b * 2097152 + (size_t)(h * 64 + sr) * 2048 + kt * 64 + skc * 8),
                AS3U(lbV), 16, 0, 0);
        }
    }

    // epilogue: reduce l across quads, normalize, write ctx directly.
    float l = l_r;
    l += __shfl_xor(l, 16);
    l += __shfl_xor(l, 32);
    const float inv = 1.f / l;
    const size_t row = (size_t)(b * 2048 + qb * 128 + wq + l16);
#pragma unroll
    for (int md = 0; md < 4; ++md) {
        ushort4 pk;
#pragma unroll
        for (int j = 0; j < 4; ++j)
            ((ushort*)&pk)[j] = f2bf(o[md][j] * inv);
        *(ushort4*)&ctx[row * 1024 + h * 64 + md * 16 + quad * 4] = pk;
    }
}

// ---------------------------------------------------------------------------
// Workspace layout (MB offsets), total 78 MB:
//   [0,16M)   A0  } reused: qkv bf16 [0,24M), Vt [24M,32M), ctx [32M,40M)
//   [16M,32M) A1  }
//   [32M,49M) H_a } dead after FFT -> ctx reuses [32M,40M)
//   [49M,54M) H_p
//   [54M,58M) P0   [58M,62M) P1
//   [62M,68M) WaT  [68M,70M) WpT  [70M,78M) x_bf
// ---------------------------------------------------------------------------
extern "C" void kernel_launch(void* const* d_in, const int* in_sizes, int n_in,
                              void* d_out, int out_size, void* d_ws, size_t ws_size,
                              hipStream_t stream) {
    const float* x        = (const float*)d_in[0];
    const float* attn_re  = (const float*)d_in[1];
    const float* attn_im  = (const float*)d_in[2];
    const int*   attn_idx = (const int*)d_in[3];
    const float* attn_sc  = (const float*)d_in[4];
    const float* proj_re  = (const float*)d_in[5];
    const float* proj_im  = (const float*)d_in[6];
    const int*   proj_idx = (const int*)d_in[7];
    const float* proj_sc  = (const float*)d_in[8];
    const float* attn_b   = (const float*)d_in[9];
    const float* proj_b   = (const float*)d_in[10];
    float* out = (float*)d_out;

    const size_t MB = 1048576;
    char* w = (char*)d_ws;
    float2* A0  = (float2*)(w);
    float2* A1  = (float2*)(w + 16 * MB);
    float2* Ha  = (float2*)(w + 32 * MB);
    float2* Hp  = (float2*)(w + 49 * MB);
    float2* P0  = (float2*)(w + 54 * MB);
    float2* P1  = (float2*)(w + 58 * MB);
    ushort* WaT = (ushort*)(w + 62 * MB);
    ushort* WpT = (ushort*)(w + 68 * MB);
    ushort* x_bf= (ushort*)(w + 70 * MB);
    ushort* qkvb= (ushort*)(w);
    ushort* Vt  = (ushort*)(w + 24 * MB);
    ushort* ctx = (ushort*)(w + 32 * MB);

    // one memset covers Ha [32M,~48.8M) and Hp [49M,~53.2M) (gap is dead)
    hipMemsetAsync(w + 32 * MB, 0, 22 * MB, stream);

    // x->bf16 ∥ scatter (after memset: scatter writes into Ha/Hp)
    x_scatter<<<6656, 256, 0, stream>>>(
        x, x_bf, attn_re, attn_im, attn_idx, Ha, proj_re, proj_im, proj_idx, Hp);

    // FUSED stage 1 (pack + first butterfly), both chains: Ha->A1, Hp->P1
    fft_pack1<<<2048, 256, 0, stream>>>(
        Ha, A1, (float)(2.0 * M_PI / ATTN_PAD_C), 1024,
        Hp, P1, (float)(2.0 * M_PI / PROJ_PAD_C), PROJ_NC / 2, PROJ_NC / 2);

    // remaining paired iFFT stages
    fft_r64_dual<<<1280, 256, 0, stream>>>(A1, A0, 6,  ATTN_NC >> 9,  1024,
                                           P1, P0, 1,  PROJ_NC >> 4);
    fft_r64_dual<<<1280, 256, 0, stream>>>(A0, A1, 12, ATTN_NC >> 15, 1024,
                                           P0, P1, 7,  PROJ_NC >> 10);
    fft_r8_r64 <<<1280, 256, 0, stream>>>(A1, A0, 18, (float)(M_PI / 4.0),
                                          ATTN_NC / 8, 1024,
                                          P1, P0, 13, PROJ_NC >> 16);
    // transpose both weight matrices
    transpose_dual<<<4096, 256, 0, stream>>>(A0, WaT, attn_sc, P0, WpT, proj_sc);

    // qkv = x @ Wa + bias (bf16 out; V third written transposed into Vt)
    gemm_bt_mfma<1><<<dim3(3072 / 128, 4096 / 128), 256, 0, stream>>>(
        x_bf, WaT, attn_b, qkvb, Vt, 4096, 3072, 1024);

    // attention: 8-wave blocks, rotating prefetch, XCD remap, ctx out
    attn_fwd_mfma<<<512, 512, 0, stream>>>(qkvb, Vt, ctx);

    gemm_bt_mfma<0><<<dim3(1024 / 128, 4096 / 128), 256, 0, stream>>>(
        ctx, WpT, proj_b, out, (ushort*)nullptr, 4096, 1024, 1024);
}